// Round 16
// baseline (108.743 us; speedup 1.0000x reference)
//
#include <hip/hip_runtime.h>
#include <math.h>

typedef short short8 __attribute__((ext_vector_type(8)));
typedef float f32x4  __attribute__((ext_vector_type(4)));

constexpr int Ssz = 512, Dsz = 64, Lsz = 4, Bsz = 32;
constexpr int TI = 32, TJ = 64;

// ---- workspace layout (10 MB) ----
constexpr size_t XBF_OFF = 0;                        // [B][64 d][512 s] bf16 = 2 MB
constexpr size_t RM_OFF  = 2u * 1024 * 1024;         // [L*B][8 jblk][512 i] u64 : bits of adj[i][j]  (dir=1)
constexpr size_t CM_OFF  = RM_OFF + 4u * 1024 * 1024;// [L*B][8 jblk][512 i] u64 : bits of adj[j][i]  (dir=0)
constexpr size_t WS_NEED = CM_OFF + 4u * 1024 * 1024;// 10 MB

// ---- main-kernel LDS: MFMA epilogue ----
constexpr int YS_B   = 0;                  // 8 waves x [32][64] bf16 slices = 32768 B
constexpr int DEG_B2 = 32768;              // 8 x 32 f32 = 1024 B
constexpr int FIN_B2 = DEG_B2 + 1024;      // [64 c][33 i] f32 = 8448 B
constexpr int MAIN_SMEM = FIN_B2 + 8448;   // 42240 B

// ---- fallback epilogue LDS overlay (floats) ----
constexpr int YBs = 69;
constexpr int YB_f = 0;                    // [32][69]
constexpr int WBs = 68;
constexpr int WB_f = YB_f + 32 * YBs;      // [64][68]
constexpr int DG_f = WB_f + 64 * WBs;      // [32]
constexpr int WG_f = DG_f + 32;            // [64]
constexpr int BB_f = WG_f + 64;            // [64]
constexpr int EPI_FLOATS = BB_f + 64;      // 6720 floats = 26880 B

__device__ __forceinline__ unsigned short f2bf(float x) {
    union { float f; unsigned u; } v; v.f = x;
    unsigned r = v.u + 0x7FFFu + ((v.u >> 16) & 1u);   // RNE
    return (unsigned short)(r >> 16);
}

// ============ P1: X [B][S][D] f32 -> Xbf^T [B][D][S] bf16 ============
__global__ __launch_bounds__(256)
void xpose_kernel(const float* __restrict__ X, unsigned short* __restrict__ xbf)
{
    __shared__ unsigned short t[64][66];
    const int b = blockIdx.y, s0 = blockIdx.x * 64;
    const int tid = threadIdx.x;
    const int c = tid & 63, r4 = tid >> 6;
    const float* Xb = X + (size_t)b * Ssz * Dsz;
#pragma unroll
    for (int k = 0; k < 16; ++k) {
        const int s = r4 + 4 * k;
        t[s][c] = f2bf(Xb[(size_t)(s0 + s) * Dsz + c]);   // coalesced read
    }
    __syncthreads();
    unsigned short* o = xbf + (size_t)b * Dsz * Ssz;
#pragma unroll
    for (int k = 0; k < 16; ++k) {
        const int d = r4 + 4 * k;
        o[(size_t)d * Ssz + s0 + c] = t[c][d];            // coalesced write
    }
}

// ============ P2: adjacency -> row/col bitmasks (one streaming sweep) ============
__global__ __launch_bounds__(256)
void mask_kernel(const int* __restrict__ adj,
                 unsigned long long* __restrict__ rm,
                 unsigned long long* __restrict__ cm)
{
    const int tid  = threadIdx.x;
    const int lane = tid & 63;
    const int wt   = blockIdx.x * 4 + (tid >> 6);   // wave-tile 0..8191
    const int lb   = wt >> 6;                       // (l*B + b)
    const int rem  = wt & 63;
    const int r1t  = (rem >> 3) * 64;               // first-index tile base
    const int r2t  = (rem & 7) * 64;                // second-index tile base
    const int* A = adj + (size_t)lb * Ssz * Ssz;

    unsigned long long c = 0ull, rmine = 0ull;
#pragma unroll 4
    for (int j = 0; j < 64; ++j) {
        const int a = A[(size_t)(r1t + j) * Ssz + r2t + lane];   // coalesced 256B/wave
        const unsigned long long bal = __ballot(a != 0);          // bits over r2 (fixed r1t+j)
        if (lane == j) rmine = bal;
        c |= ((unsigned long long)(a != 0)) << j;                 // bits over r1 (fixed r2=lane)
    }
    rm[((size_t)lb * 8 + (r2t >> 6)) * 512 + r1t + lane] = rmine;
    cm[((size_t)lb * 8 + (r1t >> 6)) * 512 + r2t + lane] = c;
}

// ============ main: barrier-free MFMA aggregation + MFMA epilogue ============
__global__ __launch_bounds__(512, 4)
void rfgcn_main(const float* __restrict__ X,
                const unsigned short* __restrict__ xbf,
                const unsigned long long* __restrict__ rm,
                const unsigned long long* __restrict__ cm,
                const float* __restrict__ nw,
                const float* __restrict__ W_in,  const float* __restrict__ b_in,
                const float* __restrict__ wg_in, const float* __restrict__ bg_in,
                const float* __restrict__ W_out, const float* __restrict__ b_out,
                const float* __restrict__ wg_out,const float* __restrict__ bg_out,
                float* __restrict__ out)
{
    __shared__ __align__(16) char smem[MAIN_SMEM];
    short* sm16 = (short*)smem;
    float* degf = (float*)(smem + DEG_B2);
    float* finf = (float*)(smem + FIN_B2);

    const int tid  = threadIdx.x;
    const int b    = blockIdx.y;
    const int i0   = blockIdx.x * TI;
    const int w    = tid >> 6;
    const int lane = tid & 63;
    const int dir  = w & 1;          // 0 = in (adj[j][i]) -> cm ; 1 = out (adj[i][j]) -> rm
    const int wl   = w >> 1;         // label
    const int lm   = lane & 15;
    const int lg   = lane >> 4;

    // zero fin accumulator (barrier before first atomic use, below)
    for (int k = tid; k < 64 * 33; k += 512) finf[k] = 0.f;

    f32x4 acc[2][4];
    f32x4 dacc[2];
#pragma unroll
    for (int rt = 0; rt < 2; ++rt) {
#pragma unroll
        for (int nt = 0; nt < 4; ++nt) acc[rt][nt] = (f32x4){0.f, 0.f, 0.f, 0.f};
        dacc[rt] = (f32x4){0.f, 0.f, 0.f, 0.f};
    }
    const short8 ones = {(short)0x3F80, (short)0x3F80, (short)0x3F80, (short)0x3F80,
                         (short)0x3F80, (short)0x3F80, (short)0x3F80, (short)0x3F80};

    const unsigned long long* Mb = (dir ? rm : cm) + (size_t)(wl * Bsz + b) * 8 * 512;
    const unsigned short* xp0 = xbf + (size_t)b * Dsz * Ssz;

    // -------- aggregation: Y = A_dir · X  (r15-verified, no barriers, no LDS) ----
    for (int jc = 0; jc < 8; ++jc) {
        const unsigned long long m0 = Mb[(size_t)jc * 512 + i0 + lm];
        const unsigned long long m1 = Mb[(size_t)jc * 512 + i0 + 16 + lm];
        const unsigned short* xp = xp0 + jc * 64;
#pragma unroll
        for (int ks = 0; ks < 2; ++ks) {
            short8 bh[4];
#pragma unroll
            for (int nt = 0; nt < 4; ++nt)
                bh[nt] = *(const short8*)(xp + (size_t)(16 * nt + lm) * Ssz + 8 * (4 * ks + lg));
#pragma unroll
            for (int rt = 0; rt < 2; ++rt) {
                const unsigned bytev = (unsigned)((rt ? m1 : m0) >> (32 * ks + 8 * lg)) & 0xFFu;
                short8 af;
#pragma unroll
                for (int jj = 0; jj < 8; ++jj)
                    af[jj] = ((bytev >> jj) & 1u) ? (short)0x3F80 : (short)0;
#pragma unroll
                for (int nt = 0; nt < 4; ++nt)
                    acc[rt][nt] = __builtin_amdgcn_mfma_f32_16x16x32_bf16(af, bh[nt], acc[rt][nt], 0, 0, 0);
                dacc[rt] = __builtin_amdgcn_mfma_f32_16x16x32_bf16(af, ones, dacc[rt], 0, 0, 0);
            }
        }
    }

    // -------- MFMA epilogue (r11-verified math): T^T = W'^T · Y^T ----
    // 1) wave-private Y slice [32][64] bf16 (16B-granule swizzle); no barrier needed
    short* Ys = sm16 + YS_B / 2 + w * 2048;
#pragma unroll
    for (int rt = 0; rt < 2; ++rt)
#pragma unroll
        for (int nt = 0; nt < 4; ++nt)
#pragma unroll
            for (int r = 0; r < 4; ++r) {
                const int row = 16 * rt + 4 * lg + r;
                const int gs  = (((2 * nt + (lm >> 3)) ^ (row & 7)) << 3) + (lm & 7);
                Ys[row * 64 + gs] = (short)f2bf(acc[rt][nt][r]);   // e = 16*nt+lm
            }
    if (lm == 0) {
#pragma unroll
        for (int rt = 0; rt < 2; ++rt)
#pragma unroll
            for (int r = 0; r < 4; ++r)
                degf[w * 32 + 16 * rt + 4 * lg + r] = dacc[rt][r];
    }

    // 2) Y^T B-fragments: lane holds B[n=i=16it+lm][k=e=8lg+j+32ks]
    short8 by[2][2];
#pragma unroll
    for (int it = 0; it < 2; ++it)
#pragma unroll
        for (int ks = 0; ks < 2; ++ks) {
            const int i  = 16 * it + lm;
            const int gs = ((lg + 4 * ks) ^ (i & 7)) << 3;
            by[it][ks] = *(const short8*)(Ys + i * 64 + gs);
        }
    float degv[2];
#pragma unroll
    for (int it = 0; it < 2; ++it) degv[it] = degf[w * 32 + 16 * it + lm];

    // 3) W'^T A-fragments from global (64 KB total, L2-hot), MFMA into accT
    const float* Wp  = (dir ? W_out  : W_in)  + wl * Dsz * Dsz;
    const float* wgp = (dir ? wg_out : wg_in) + wl * Dsz;
    const float* bp  = (dir ? b_out  : b_in)  + wl * Dsz;
    const float  bgv = (dir ? bg_out : bg_in)[wl];

    f32x4 accT[5][2];   // [c-tile ct (ct=4 -> gate)][i-tile it]
#pragma unroll
    for (int ct = 0; ct < 5; ++ct)
#pragma unroll
        for (int it = 0; it < 2; ++it) accT[ct][it] = (f32x4){0.f, 0.f, 0.f, 0.f};

#pragma unroll
    for (int ct = 0; ct < 5; ++ct) {
#pragma unroll
        for (int ks = 0; ks < 2; ++ks) {
            short8 aw;
            if (ct < 4) {
                const int c = 16 * ct + lm;
#pragma unroll
                for (int j = 0; j < 8; ++j)
                    aw[j] = (short)f2bf(Wp[(size_t)(8 * lg + j + 32 * ks) * Dsz + c]);
            } else {
#pragma unroll
                for (int j = 0; j < 8; ++j)
                    aw[j] = (short)f2bf(wgp[8 * lg + j + 32 * ks]);   // gate rows: wg replicated
            }
#pragma unroll
            for (int it = 0; it < 2; ++it)
                accT[ct][it] = __builtin_amdgcn_mfma_f32_16x16x32_bf16(aw, by[it][ks], accT[ct][it], 0, 0, 0);
        }
    }

    // 4) gate -> sigmoid; deg*b correction; accumulate fin^T[c][i] (LDS atomics)
    float sg[2];
#pragma unroll
    for (int it = 0; it < 2; ++it) {
        const float g = accT[4][it][0] + degv[it] * bgv;   // replicated over r
        sg[it] = 1.f / (1.f + expf(-g));
    }
    __syncthreads();   // finf zero-init visible to all waves before atomics
#pragma unroll
    for (int ct = 0; ct < 4; ++ct)
#pragma unroll
        for (int r = 0; r < 4; ++r) {
            const int c = 16 * ct + 4 * lg + r;
            const float bc = bp[c];
#pragma unroll
            for (int it = 0; it < 2; ++it) {
                const float v = (accT[ct][it][r] + degv[it] * bc) * sg[it];
                atomicAdd(&finf[c * 33 + 16 * it + lm], v);
            }
        }

    __syncthreads();   // fin complete

    // 5) writeout: out = (X + fin) / (3*nw)
    const float inv = 1.f / (3.f * nw[b]);
    const float* Xb = X + (size_t)b * Ssz * Dsz;
    const int oi = tid >> 4;           // row 0..31
    const int c4 = (tid & 15) * 4;     // col group
    const float4 xv = *(const float4*)&Xb[(size_t)(i0 + oi) * Dsz + c4];
    float4 o;
    o.x = (xv.x + finf[(c4 + 0) * 33 + oi]) * inv;
    o.y = (xv.y + finf[(c4 + 1) * 33 + oi]) * inv;
    o.z = (xv.z + finf[(c4 + 2) * 33 + oi]) * inv;
    o.w = (xv.w + finf[(c4 + 3) * 33 + oi]) * inv;
    *(float4*)(out + ((size_t)b * Ssz + i0 + oi) * Dsz + c4) = o;
}

// ============ fallback (r12 kernel, 76 us verified) — used if ws too small ============
constexpr int XTb[2] = {0, 4096};
constexpr int FB_SMEM = EPI_FLOATS * 4;

__global__ __launch_bounds__(512, 4)
void rfgcn_fallback(const float* __restrict__ X, const int* __restrict__ adj,
                    const float* __restrict__ nw,
                    const float* __restrict__ W_in,  const float* __restrict__ b_in,
                    const float* __restrict__ wg_in, const float* __restrict__ bg_in,
                    const float* __restrict__ W_out, const float* __restrict__ b_out,
                    const float* __restrict__ wg_out,const float* __restrict__ bg_out,
                    float* __restrict__ out)
{
    __shared__ __align__(16) char smem[FB_SMEM];
    short* sm16 = (short*)smem;
    float* smf  = (float*)smem;

    const int tid  = threadIdx.x;
    const int b    = blockIdx.y;
    const int i0   = blockIdx.x * TI;
    const int w    = tid >> 6;
    const int lane = tid & 63;
    const int dir  = w & 1;
    const int wl   = w >> 1;
    const int lm   = lane & 15;
    const int lg   = lane >> 4;

    f32x4 acc[2][4];
    f32x4 dacc[2];
#pragma unroll
    for (int rt = 0; rt < 2; ++rt) {
#pragma unroll
        for (int nt = 0; nt < 4; ++nt) acc[rt][nt] = (f32x4){0.f, 0.f, 0.f, 0.f};
        dacc[rt] = (f32x4){0.f, 0.f, 0.f, 0.f};
    }
    const short8 ones = {(short)0x3F80, (short)0x3F80, (short)0x3F80, (short)0x3F80,
                         (short)0x3F80, (short)0x3F80, (short)0x3F80, (short)0x3F80};

    const float* Xb = X + (size_t)b * Ssz * Dsz;
    const int*   Ab = adj + ((size_t)wl * Bsz + b) * Ssz * Ssz;

    float xv[8];
    int   aR[32];

#define ADJ_LOAD(T)                                                              \
    {                                                                            \
        const int J0 = (T) * TJ;                                                 \
        if (dir == 0) {                                                          \
            _Pragma("unroll")                                                    \
            for (int rt = 0; rt < 2; ++rt)                                       \
                _Pragma("unroll")                                                \
                for (int ks = 0; ks < 2; ++ks)                                   \
                    _Pragma("unroll")                                            \
                    for (int j = 0; j < 8; ++j)                                  \
                        aR[rt * 16 + ks * 8 + j] =                               \
                            Ab[(size_t)(J0 + 32 * ks + 8 * lg + j) * Ssz + i0 + 16 * rt + lm]; \
        } else {                                                                 \
            _Pragma("unroll")                                                    \
            for (int rt = 0; rt < 2; ++rt)                                       \
                _Pragma("unroll")                                                \
                for (int ks = 0; ks < 2; ++ks) {                                 \
                    const int* p = &Ab[(size_t)(i0 + 16 * rt + lm) * Ssz + J0 + 32 * ks + 8 * lg]; \
                    const int4 q0 = *(const int4*)p;                             \
                    const int4 q1 = *(const int4*)(p + 4);                       \
                    aR[rt * 16 + ks * 8 + 0] = q0.x; aR[rt * 16 + ks * 8 + 1] = q0.y; \
                    aR[rt * 16 + ks * 8 + 2] = q0.z; aR[rt * 16 + ks * 8 + 3] = q0.w; \
                    aR[rt * 16 + ks * 8 + 4] = q1.x; aR[rt * 16 + ks * 8 + 5] = q1.y; \
                    aR[rt * 16 + ks * 8 + 6] = q1.z; aR[rt * 16 + ks * 8 + 7] = q1.w; \
                }                                                                \
        }                                                                        \
    }
#define X_LOAD(T)                                                                \
    {                                                                            \
        const int J0 = (T) * TJ;                                                 \
        _Pragma("unroll")                                                        \
        for (int s = 0; s < 8; ++s) xv[s] = Xb[(size_t)(J0 + 8 * w + s) * Dsz + lane]; \
    }
#define X_WRITE(BUF)                                                             \
    {                                                                            \
        short8 hi;                                                               \
        _Pragma("unroll")                                                        \
        for (int s = 0; s < 8; ++s) hi[s] = (short)f2bf(xv[s]);                  \
        const int g = w ^ (lane & 7);                                            \
        *(short8*)(sm16 + XTb[BUF] + lane * 64 + g * 8) = hi;                    \
    }

    X_LOAD(0)
    X_WRITE(0)
    ADJ_LOAD(0)
    X_LOAD(1)
    __syncthreads();

    for (int t = 0; t < 8; ++t) {
        const int cur = t & 1;
        short8 af[2][2];
#pragma unroll
        for (int rt = 0; rt < 2; ++rt)
#pragma unroll
            for (int ks = 0; ks < 2; ++ks)
#pragma unroll
                for (int j = 0; j < 8; ++j)
                    af[rt][ks][j] = aR[rt * 16 + ks * 8 + j] ? (short)0x3F80 : (short)0;

        if (t < 7) ADJ_LOAD(t + 1)
        if (t < 7) X_WRITE(cur ^ 1)
        if (t < 6) X_LOAD(t + 2)

#pragma unroll
        for (int ks = 0; ks < 2; ++ks) {
            short8 bh[4];
#pragma unroll
            for (int nt = 0; nt < 4; ++nt) {
                const int d = nt * 16 + lm;
                const int g = (4 * ks + lg) ^ (d & 7);
                bh[nt] = *(const short8*)(sm16 + XTb[cur] + d * 64 + g * 8);
            }
#pragma unroll
            for (int rt = 0; rt < 2; ++rt) {
#pragma unroll
                for (int nt = 0; nt < 4; ++nt)
                    acc[rt][nt] = __builtin_amdgcn_mfma_f32_16x16x32_bf16(af[rt][ks], bh[nt], acc[rt][nt], 0, 0, 0);
                dacc[rt] = __builtin_amdgcn_mfma_f32_16x16x32_bf16(af[rt][ks], ones, dacc[rt], 0, 0, 0);
            }
        }
        __syncthreads();
    }
#undef ADJ_LOAD
#undef X_LOAD
#undef X_WRITE

    const int ei  = tid & 31;
    const int ecg = tid >> 5;
    float fin[4];
#pragma unroll
    for (int q = 0; q < 4; ++q) fin[q] = 0.f;

#pragma unroll
    for (int l = 0; l < Lsz; ++l) {
#pragma unroll
        for (int d2 = 0; d2 < 2; ++d2) {
            if (l + d2) __syncthreads();
            if (dir == d2 && wl == l) {
#pragma unroll
                for (int rt = 0; rt < 2; ++rt)
#pragma unroll
                    for (int nt = 0; nt < 4; ++nt)
#pragma unroll
                        for (int r = 0; r < 4; ++r)
                            smf[YB_f + (16 * rt + 4 * lg + r) * YBs + nt * 16 + lm] = acc[rt][nt][r];
                if (lm == 0)
#pragma unroll
                    for (int rt = 0; rt < 2; ++rt)
#pragma unroll
                        for (int r = 0; r < 4; ++r)
                            smf[DG_f + 16 * rt + 4 * lg + r] = dacc[rt][r];
            }
            const float* Wp = (d2 ? W_out : W_in) + l * Dsz * Dsz;
            {
                const int r = tid >> 3, c8 = tid & 7;
                *(float4*)&smf[WB_f + r * WBs + 8 * c8]     = *(const float4*)&Wp[r * Dsz + 8 * c8];
                *(float4*)&smf[WB_f + r * WBs + 8 * c8 + 4] = *(const float4*)&Wp[r * Dsz + 8 * c8 + 4];
            }
            const float* wgp = (d2 ? wg_out : wg_in) + l * Dsz;
            const float* bp  = (d2 ? b_out  : b_in)  + l * Dsz;
            if (tid < 64)        smf[WG_f + tid]      = wgp[tid];
            else if (tid < 128)  smf[BB_f + tid - 64] = bp[tid - 64];
            const float bgs = (d2 ? bg_out : bg_in)[l];
            __syncthreads();

            const float dg = smf[DG_f + ei];
            float tq[4];
#pragma unroll
            for (int q = 0; q < 4; ++q) tq[q] = dg * smf[BB_f + 4 * ecg + q];
            float gate = dg * bgs;
#pragma unroll 4
            for (int e = 0; e < 64; ++e) {
                const float yv = smf[YB_f + ei * YBs + e];
                gate += yv * smf[WG_f + e];
#pragma unroll
                for (int q = 0; q < 4; ++q) tq[q] += yv * smf[WB_f + e * WBs + 4 * ecg + q];
            }
            const float sg = 1.f / (1.f + expf(-gate));
#pragma unroll
            for (int q = 0; q < 4; ++q) fin[q] += tq[q] * sg;
        }
    }

    const float inv = 1.f / (3.f * nw[b]);
    const float4 xr = *(const float4*)&Xb[(size_t)(i0 + ei) * Dsz + 4 * ecg];
    float4 o;
    o.x = (xr.x + fin[0]) * inv;
    o.y = (xr.y + fin[1]) * inv;
    o.z = (xr.z + fin[2]) * inv;
    o.w = (xr.w + fin[3]) * inv;
    *(float4*)(out + ((size_t)b * Ssz + i0 + ei) * Dsz + 4 * ecg) = o;
}

extern "C" void kernel_launch(void* const* d_in, const int* in_sizes, int n_in,
                              void* d_out, int out_size, void* d_ws, size_t ws_size,
                              hipStream_t stream)
{
    const float* X      = (const float*)d_in[0];
    const int*   adj    = (const int*)  d_in[1];
    const float* nw     = (const float*)d_in[2];
    const float* W_in   = (const float*)d_in[3];
    const float* b_in   = (const float*)d_in[4];
    const float* wg_in  = (const float*)d_in[5];
    const float* bg_in  = (const float*)d_in[6];
    const float* W_out  = (const float*)d_in[7];
    const float* b_out  = (const float*)d_in[8];
    const float* wg_out = (const float*)d_in[9];
    const float* bg_out = (const float*)d_in[10];
    float* out = (float*)d_out;

    if (ws_size >= WS_NEED) {
        unsigned short*      xbf = (unsigned short*)((char*)d_ws + XBF_OFF);
        unsigned long long*  rmp = (unsigned long long*)((char*)d_ws + RM_OFF);
        unsigned long long*  cmp = (unsigned long long*)((char*)d_ws + CM_OFF);
        hipLaunchKernelGGL(xpose_kernel, dim3(8, 32), dim3(256), 0, stream, X, xbf);
        hipLaunchKernelGGL(mask_kernel, dim3(2048), dim3(256), 0, stream, adj, rmp, cmp);
        hipLaunchKernelGGL(rfgcn_main, dim3(Ssz / TI, Bsz), dim3(512), 0, stream,
                           X, xbf, rmp, cmp, nw, W_in, b_in, wg_in, bg_in,
                           W_out, b_out, wg_out, bg_out, out);
    } else {
        hipLaunchKernelGGL(rfgcn_fallback, dim3(Ssz / TI, Bsz), dim3(512), 0, stream,
                           X, adj, nw, W_in, b_in, wg_in, bg_in,
                           W_out, b_out, wg_out, bg_out, out);
    }
}

// Round 17
// 107.990 us; speedup vs baseline: 1.0070x; 1.0070x over previous
//
#include <hip/hip_runtime.h>
#include <math.h>

typedef short short8 __attribute__((ext_vector_type(8)));
typedef float f32x4  __attribute__((ext_vector_type(4)));

constexpr int Ssz = 512, Dsz = 64, Lsz = 4, Bsz = 32;
constexpr int TI = 32, TJ = 64;

// ---- workspace layout (10 MB) ----
constexpr size_t XBF_OFF = 0;                        // [B][64 d][512 s] bf16 = 2 MB
constexpr size_t RM_OFF  = 2u * 1024 * 1024;         // [L*B][8 jblk][512 i] u64 : bits of adj[i][j]  (dir=1)
constexpr size_t CM_OFF  = RM_OFF + 4u * 1024 * 1024;// [L*B][8 jblk][512 i] u64 : bits of adj[j][i]  (dir=0)
constexpr size_t WS_NEED = CM_OFF + 4u * 1024 * 1024;// 10 MB

// ---- main-kernel LDS: MFMA epilogue ----
constexpr int YS_B   = 0;                  // 8 waves x [32][64] bf16 slices = 32768 B
constexpr int DEG_B2 = 32768;              // 8 x 32 f32 = 1024 B
constexpr int FIN_B2 = DEG_B2 + 1024;      // [64 c][33 i] f32 = 8448 B
constexpr int MAIN_SMEM = FIN_B2 + 8448;   // 42240 B

// ---- fallback epilogue LDS overlay (floats) ----
constexpr int YBs = 69;
constexpr int YB_f = 0;                    // [32][69]
constexpr int WBs = 68;
constexpr int WB_f = YB_f + 32 * YBs;      // [64][68]
constexpr int DG_f = WB_f + 64 * WBs;      // [32]
constexpr int WG_f = DG_f + 32;            // [64]
constexpr int BB_f = WG_f + 64;            // [64]
constexpr int EPI_FLOATS = BB_f + 64;      // 6720 floats = 26880 B

__device__ __forceinline__ unsigned short f2bf(float x) {
    union { float f; unsigned u; } v; v.f = x;
    unsigned r = v.u + 0x7FFFu + ((v.u >> 16) & 1u);   // RNE
    return (unsigned short)(r >> 16);
}

// ============ P1: X [B][S][D] f32 -> Xbf^T [B][D][S] bf16 ============
__global__ __launch_bounds__(256)
void xpose_kernel(const float* __restrict__ X, unsigned short* __restrict__ xbf)
{
    __shared__ unsigned short t[64][66];
    const int b = blockIdx.y, s0 = blockIdx.x * 64;
    const int tid = threadIdx.x;
    const int c = tid & 63, r4 = tid >> 6;
    const float* Xb = X + (size_t)b * Ssz * Dsz;
#pragma unroll
    for (int k = 0; k < 16; ++k) {
        const int s = r4 + 4 * k;
        t[s][c] = f2bf(Xb[(size_t)(s0 + s) * Dsz + c]);   // coalesced read
    }
    __syncthreads();
    unsigned short* o = xbf + (size_t)b * Dsz * Ssz;
#pragma unroll
    for (int k = 0; k < 16; ++k) {
        const int d = r4 + 4 * k;
        o[(size_t)d * Ssz + s0 + c] = t[c][d];            // coalesced write
    }
}

// ============ P2: adjacency -> row/col bitmasks (one streaming sweep) ============
__global__ __launch_bounds__(256)
void mask_kernel(const int* __restrict__ adj,
                 unsigned long long* __restrict__ rm,
                 unsigned long long* __restrict__ cm)
{
    const int tid  = threadIdx.x;
    const int lane = tid & 63;
    const int wt   = blockIdx.x * 4 + (tid >> 6);   // wave-tile 0..8191
    const int lb   = wt >> 6;                       // (l*B + b)
    const int rem  = wt & 63;
    const int r1t  = (rem >> 3) * 64;               // first-index tile base
    const int r2t  = (rem & 7) * 64;                // second-index tile base
    const int* A = adj + (size_t)lb * Ssz * Ssz;

    unsigned long long c = 0ull, rmine = 0ull;
#pragma unroll 4
    for (int j = 0; j < 64; ++j) {
        const int a = A[(size_t)(r1t + j) * Ssz + r2t + lane];   // coalesced 256B/wave
        const unsigned long long bal = __ballot(a != 0);          // bits over r2 (fixed r1t+j)
        if (lane == j) rmine = bal;
        c |= ((unsigned long long)(a != 0)) << j;                 // bits over r1 (fixed r2=lane)
    }
    rm[((size_t)lb * 8 + (r2t >> 6)) * 512 + r1t + lane] = rmine;
    cm[((size_t)lb * 8 + (r1t >> 6)) * 512 + r2t + lane] = c;
}

// ============ main: barrier-free MFMA aggregation + MFMA epilogue ============
__global__ __launch_bounds__(512, 2)      // (512,2): VGPR cap 256 -> no spill (r16's (512,4) gave 56 VGPR + scratch thrash)
void rfgcn_main(const float* __restrict__ X,
                const unsigned short* __restrict__ xbf,
                const unsigned long long* __restrict__ rm,
                const unsigned long long* __restrict__ cm,
                const float* __restrict__ nw,
                const float* __restrict__ W_in,  const float* __restrict__ b_in,
                const float* __restrict__ wg_in, const float* __restrict__ bg_in,
                const float* __restrict__ W_out, const float* __restrict__ b_out,
                const float* __restrict__ wg_out,const float* __restrict__ bg_out,
                float* __restrict__ out)
{
    __shared__ __align__(16) char smem[MAIN_SMEM];
    short* sm16 = (short*)smem;
    float* degf = (float*)(smem + DEG_B2);
    float* finf = (float*)(smem + FIN_B2);

    const int tid  = threadIdx.x;
    const int b    = blockIdx.y;
    const int i0   = blockIdx.x * TI;
    const int w    = tid >> 6;
    const int lane = tid & 63;
    const int dir  = w & 1;          // 0 = in (adj[j][i]) -> cm ; 1 = out (adj[i][j]) -> rm
    const int wl   = w >> 1;         // label
    const int lm   = lane & 15;
    const int lg   = lane >> 4;

    // zero fin accumulator (barrier before first atomic use, below)
    for (int k = tid; k < 64 * 33; k += 512) finf[k] = 0.f;

    f32x4 acc[2][4];
    f32x4 dacc[2];
#pragma unroll
    for (int rt = 0; rt < 2; ++rt) {
#pragma unroll
        for (int nt = 0; nt < 4; ++nt) acc[rt][nt] = (f32x4){0.f, 0.f, 0.f, 0.f};
        dacc[rt] = (f32x4){0.f, 0.f, 0.f, 0.f};
    }
    const short8 ones = {(short)0x3F80, (short)0x3F80, (short)0x3F80, (short)0x3F80,
                         (short)0x3F80, (short)0x3F80, (short)0x3F80, (short)0x3F80};

    const unsigned long long* Mb = (dir ? rm : cm) + (size_t)(wl * Bsz + b) * 8 * 512;
    const unsigned short* xp0 = xbf + (size_t)b * Dsz * Ssz;

    // -------- aggregation: Y = A_dir · X  (no barriers, no LDS) ----
    for (int jc = 0; jc < 8; ++jc) {
        const unsigned long long m0 = Mb[(size_t)jc * 512 + i0 + lm];
        const unsigned long long m1 = Mb[(size_t)jc * 512 + i0 + 16 + lm];
        const unsigned short* xp = xp0 + jc * 64;
#pragma unroll
        for (int ks = 0; ks < 2; ++ks) {
            short8 bh[4];
#pragma unroll
            for (int nt = 0; nt < 4; ++nt)
                bh[nt] = *(const short8*)(xp + (size_t)(16 * nt + lm) * Ssz + 8 * (4 * ks + lg));
#pragma unroll
            for (int rt = 0; rt < 2; ++rt) {
                const unsigned bytev = (unsigned)((rt ? m1 : m0) >> (32 * ks + 8 * lg)) & 0xFFu;
                short8 af;
#pragma unroll
                for (int jj = 0; jj < 8; ++jj)
                    af[jj] = ((bytev >> jj) & 1u) ? (short)0x3F80 : (short)0;
#pragma unroll
                for (int nt = 0; nt < 4; ++nt)
                    acc[rt][nt] = __builtin_amdgcn_mfma_f32_16x16x32_bf16(af, bh[nt], acc[rt][nt], 0, 0, 0);
                dacc[rt] = __builtin_amdgcn_mfma_f32_16x16x32_bf16(af, ones, dacc[rt], 0, 0, 0);
            }
        }
    }

    // -------- MFMA epilogue: T^T = W'^T · Y^T ----
    // 1) wave-private Y slice [32][64] bf16 (16B-granule swizzle); no barrier needed
    short* Ys = sm16 + YS_B / 2 + w * 2048;
#pragma unroll
    for (int rt = 0; rt < 2; ++rt)
#pragma unroll
        for (int nt = 0; nt < 4; ++nt)
#pragma unroll
            for (int r = 0; r < 4; ++r) {
                const int row = 16 * rt + 4 * lg + r;
                const int gs  = (((2 * nt + (lm >> 3)) ^ (row & 7)) << 3) + (lm & 7);
                Ys[row * 64 + gs] = (short)f2bf(acc[rt][nt][r]);   // e = 16*nt+lm
            }
    if (lm == 0) {
#pragma unroll
        for (int rt = 0; rt < 2; ++rt)
#pragma unroll
            for (int r = 0; r < 4; ++r)
                degf[w * 32 + 16 * rt + 4 * lg + r] = dacc[rt][r];
    }

    // 2) Y^T B-fragments: lane holds B[n=i=16it+lm][k=e=8lg+j+32ks]
    short8 by[2][2];
#pragma unroll
    for (int it = 0; it < 2; ++it)
#pragma unroll
        for (int ks = 0; ks < 2; ++ks) {
            const int i  = 16 * it + lm;
            const int gs = ((lg + 4 * ks) ^ (i & 7)) << 3;
            by[it][ks] = *(const short8*)(Ys + i * 64 + gs);
        }
    float degv[2];
#pragma unroll
    for (int it = 0; it < 2; ++it) degv[it] = degf[w * 32 + 16 * it + lm];

    // 3) W'^T A-fragments from global (64 KB total, L2-hot), MFMA into accT
    const float* Wp  = (dir ? W_out  : W_in)  + wl * Dsz * Dsz;
    const float* wgp = (dir ? wg_out : wg_in) + wl * Dsz;
    const float* bp  = (dir ? b_out  : b_in)  + wl * Dsz;
    const float  bgv = (dir ? bg_out : bg_in)[wl];

    f32x4 accT[5][2];   // [c-tile ct (ct=4 -> gate)][i-tile it]
#pragma unroll
    for (int ct = 0; ct < 5; ++ct)
#pragma unroll
        for (int it = 0; it < 2; ++it) accT[ct][it] = (f32x4){0.f, 0.f, 0.f, 0.f};

#pragma unroll
    for (int ct = 0; ct < 5; ++ct) {
#pragma unroll
        for (int ks = 0; ks < 2; ++ks) {
            short8 aw;
            if (ct < 4) {
                const int c = 16 * ct + lm;
#pragma unroll
                for (int j = 0; j < 8; ++j)
                    aw[j] = (short)f2bf(Wp[(size_t)(8 * lg + j + 32 * ks) * Dsz + c]);
            } else {
#pragma unroll
                for (int j = 0; j < 8; ++j)
                    aw[j] = (short)f2bf(wgp[8 * lg + j + 32 * ks]);   // gate rows: wg replicated
            }
#pragma unroll
            for (int it = 0; it < 2; ++it)
                accT[ct][it] = __builtin_amdgcn_mfma_f32_16x16x32_bf16(aw, by[it][ks], accT[ct][it], 0, 0, 0);
        }
    }

    // 4) gate -> sigmoid; deg*b correction; accumulate fin^T[c][i] (LDS atomics)
    float sg[2];
#pragma unroll
    for (int it = 0; it < 2; ++it) {
        const float g = accT[4][it][0] + degv[it] * bgv;   // replicated over r
        sg[it] = 1.f / (1.f + expf(-g));
    }
    __syncthreads();   // finf zero-init visible to all waves before atomics
#pragma unroll
    for (int ct = 0; ct < 4; ++ct)
#pragma unroll
        for (int r = 0; r < 4; ++r) {
            const int c = 16 * ct + 4 * lg + r;
            const float bc = bp[c];
#pragma unroll
            for (int it = 0; it < 2; ++it) {
                const float v = (accT[ct][it][r] + degv[it] * bc) * sg[it];
                atomicAdd(&finf[c * 33 + 16 * it + lm], v);
            }
        }

    __syncthreads();   // fin complete

    // 5) writeout: out = (X + fin) / (3*nw)
    const float inv = 1.f / (3.f * nw[b]);
    const float* Xb = X + (size_t)b * Ssz * Dsz;
    const int oi = tid >> 4;           // row 0..31
    const int c4 = (tid & 15) * 4;     // col group
    const float4 xv = *(const float4*)&Xb[(size_t)(i0 + oi) * Dsz + c4];
    float4 o;
    o.x = (xv.x + finf[(c4 + 0) * 33 + oi]) * inv;
    o.y = (xv.y + finf[(c4 + 1) * 33 + oi]) * inv;
    o.z = (xv.z + finf[(c4 + 2) * 33 + oi]) * inv;
    o.w = (xv.w + finf[(c4 + 3) * 33 + oi]) * inv;
    *(float4*)(out + ((size_t)b * Ssz + i0 + oi) * Dsz + c4) = o;
}

// ============ fallback (r12 kernel, 76 us verified) — used if ws too small ============
constexpr int XTb[2] = {0, 4096};
constexpr int FB_SMEM = EPI_FLOATS * 4;

__global__ __launch_bounds__(512, 4)
void rfgcn_fallback(const float* __restrict__ X, const int* __restrict__ adj,
                    const float* __restrict__ nw,
                    const float* __restrict__ W_in,  const float* __restrict__ b_in,
                    const float* __restrict__ wg_in, const float* __restrict__ bg_in,
                    const float* __restrict__ W_out, const float* __restrict__ b_out,
                    const float* __restrict__ wg_out,const float* __restrict__ bg_out,
                    float* __restrict__ out)
{
    __shared__ __align__(16) char smem[FB_SMEM];
    short* sm16 = (short*)smem;
    float* smf  = (float*)smem;

    const int tid  = threadIdx.x;
    const int b    = blockIdx.y;
    const int i0   = blockIdx.x * TI;
    const int w    = tid >> 6;
    const int lane = tid & 63;
    const int dir  = w & 1;
    const int wl   = w >> 1;
    const int lm   = lane & 15;
    const int lg   = lane >> 4;

    f32x4 acc[2][4];
    f32x4 dacc[2];
#pragma unroll
    for (int rt = 0; rt < 2; ++rt) {
#pragma unroll
        for (int nt = 0; nt < 4; ++nt) acc[rt][nt] = (f32x4){0.f, 0.f, 0.f, 0.f};
        dacc[rt] = (f32x4){0.f, 0.f, 0.f, 0.f};
    }
    const short8 ones = {(short)0x3F80, (short)0x3F80, (short)0x3F80, (short)0x3F80,
                         (short)0x3F80, (short)0x3F80, (short)0x3F80, (short)0x3F80};

    const float* Xb = X + (size_t)b * Ssz * Dsz;
    const int*   Ab = adj + ((size_t)wl * Bsz + b) * Ssz * Ssz;

    float xv[8];
    int   aR[32];

#define ADJ_LOAD(T)                                                              \
    {                                                                            \
        const int J0 = (T) * TJ;                                                 \
        if (dir == 0) {                                                          \
            _Pragma("unroll")                                                    \
            for (int rt = 0; rt < 2; ++rt)                                       \
                _Pragma("unroll")                                                \
                for (int ks = 0; ks < 2; ++ks)                                   \
                    _Pragma("unroll")                                            \
                    for (int j = 0; j < 8; ++j)                                  \
                        aR[rt * 16 + ks * 8 + j] =                               \
                            Ab[(size_t)(J0 + 32 * ks + 8 * lg + j) * Ssz + i0 + 16 * rt + lm]; \
        } else {                                                                 \
            _Pragma("unroll")                                                    \
            for (int rt = 0; rt < 2; ++rt)                                       \
                _Pragma("unroll")                                                \
                for (int ks = 0; ks < 2; ++ks) {                                 \
                    const int* p = &Ab[(size_t)(i0 + 16 * rt + lm) * Ssz + J0 + 32 * ks + 8 * lg]; \
                    const int4 q0 = *(const int4*)p;                             \
                    const int4 q1 = *(const int4*)(p + 4);                       \
                    aR[rt * 16 + ks * 8 + 0] = q0.x; aR[rt * 16 + ks * 8 + 1] = q0.y; \
                    aR[rt * 16 + ks * 8 + 2] = q0.z; aR[rt * 16 + ks * 8 + 3] = q0.w; \
                    aR[rt * 16 + ks * 8 + 4] = q1.x; aR[rt * 16 + ks * 8 + 5] = q1.y; \
                    aR[rt * 16 + ks * 8 + 6] = q1.z; aR[rt * 16 + ks * 8 + 7] = q1.w; \
                }                                                                \
        }                                                                        \
    }
#define X_LOAD(T)                                                                \
    {                                                                            \
        const int J0 = (T) * TJ;                                                 \
        _Pragma("unroll")                                                        \
        for (int s = 0; s < 8; ++s) xv[s] = Xb[(size_t)(J0 + 8 * w + s) * Dsz + lane]; \
    }
#define X_WRITE(BUF)                                                             \
    {                                                                            \
        short8 hi;                                                               \
        _Pragma("unroll")                                                        \
        for (int s = 0; s < 8; ++s) hi[s] = (short)f2bf(xv[s]);                  \
        const int g = w ^ (lane & 7);                                            \
        *(short8*)(sm16 + XTb[BUF] + lane * 64 + g * 8) = hi;                    \
    }

    X_LOAD(0)
    X_WRITE(0)
    ADJ_LOAD(0)
    X_LOAD(1)
    __syncthreads();

    for (int t = 0; t < 8; ++t) {
        const int cur = t & 1;
        short8 af[2][2];
#pragma unroll
        for (int rt = 0; rt < 2; ++rt)
#pragma unroll
            for (int ks = 0; ks < 2; ++ks)
#pragma unroll
                for (int j = 0; j < 8; ++j)
                    af[rt][ks][j] = aR[rt * 16 + ks * 8 + j] ? (short)0x3F80 : (short)0;

        if (t < 7) ADJ_LOAD(t + 1)
        if (t < 7) X_WRITE(cur ^ 1)
        if (t < 6) X_LOAD(t + 2)

#pragma unroll
        for (int ks = 0; ks < 2; ++ks) {
            short8 bh[4];
#pragma unroll
            for (int nt = 0; nt < 4; ++nt) {
                const int d = nt * 16 + lm;
                const int g = (4 * ks + lg) ^ (d & 7);
                bh[nt] = *(const short8*)(sm16 + XTb[cur] + d * 64 + g * 8);
            }
#pragma unroll
            for (int rt = 0; rt < 2; ++rt) {
#pragma unroll
                for (int nt = 0; nt < 4; ++nt)
                    acc[rt][nt] = __builtin_amdgcn_mfma_f32_16x16x32_bf16(af[rt][ks], bh[nt], acc[rt][nt], 0, 0, 0);
                dacc[rt] = __builtin_amdgcn_mfma_f32_16x16x32_bf16(af[rt][ks], ones, dacc[rt], 0, 0, 0);
            }
        }
        __syncthreads();
    }
#undef ADJ_LOAD
#undef X_LOAD
#undef X_WRITE

    const int ei  = tid & 31;
    const int ecg = tid >> 5;
    float fin[4];
#pragma unroll
    for (int q = 0; q < 4; ++q) fin[q] = 0.f;

#pragma unroll
    for (int l = 0; l < Lsz; ++l) {
#pragma unroll
        for (int d2 = 0; d2 < 2; ++d2) {
            if (l + d2) __syncthreads();
            if (dir == d2 && wl == l) {
#pragma unroll
                for (int rt = 0; rt < 2; ++rt)
#pragma unroll
                    for (int nt = 0; nt < 4; ++nt)
#pragma unroll
                        for (int r = 0; r < 4; ++r)
                            smf[YB_f + (16 * rt + 4 * lg + r) * YBs + nt * 16 + lm] = acc[rt][nt][r];
                if (lm == 0)
#pragma unroll
                    for (int rt = 0; rt < 2; ++rt)
#pragma unroll
                        for (int r = 0; r < 4; ++r)
                            smf[DG_f + 16 * rt + 4 * lg + r] = dacc[rt][r];
            }
            const float* Wp = (d2 ? W_out : W_in) + l * Dsz * Dsz;
            {
                const int r = tid >> 3, c8 = tid & 7;
                *(float4*)&smf[WB_f + r * WBs + 8 * c8]     = *(const float4*)&Wp[r * Dsz + 8 * c8];
                *(float4*)&smf[WB_f + r * WBs + 8 * c8 + 4] = *(const float4*)&Wp[r * Dsz + 8 * c8 + 4];
            }
            const float* wgp = (d2 ? wg_out : wg_in) + l * Dsz;
            const float* bp  = (d2 ? b_out  : b_in)  + l * Dsz;
            if (tid < 64)        smf[WG_f + tid]      = wgp[tid];
            else if (tid < 128)  smf[BB_f + tid - 64] = bp[tid - 64];
            const float bgs = (d2 ? bg_out : bg_in)[l];
            __syncthreads();

            const float dg = smf[DG_f + ei];
            float tq[4];
#pragma unroll
            for (int q = 0; q < 4; ++q) tq[q] = dg * smf[BB_f + 4 * ecg + q];
            float gate = dg * bgs;
#pragma unroll 4
            for (int e = 0; e < 64; ++e) {
                const float yv = smf[YB_f + ei * YBs + e];
                gate += yv * smf[WG_f + e];
#pragma unroll
                for (int q = 0; q < 4; ++q) tq[q] += yv * smf[WB_f + e * WBs + 4 * ecg + q];
            }
            const float sg = 1.f / (1.f + expf(-gate));
#pragma unroll
            for (int q = 0; q < 4; ++q) fin[q] += tq[q] * sg;
        }
    }

    const float inv = 1.f / (3.f * nw[b]);
    const float4 xr = *(const float4*)&Xb[(size_t)(i0 + ei) * Dsz + 4 * ecg];
    float4 o;
    o.x = (xr.x + fin[0]) * inv;
    o.y = (xr.y + fin[1]) * inv;
    o.z = (xr.z + fin[2]) * inv;
    o.w = (xr.w + fin[3]) * inv;
    *(float4*)(out + ((size_t)b * Ssz + i0 + ei) * Dsz + 4 * ecg) = o;
}

extern "C" void kernel_launch(void* const* d_in, const int* in_sizes, int n_in,
                              void* d_out, int out_size, void* d_ws, size_t ws_size,
                              hipStream_t stream)
{
    const float* X      = (const float*)d_in[0];
    const int*   adj    = (const int*)  d_in[1];
    const float* nw     = (const float*)d_in[2];
    const float* W_in   = (const float*)d_in[3];
    const float* b_in   = (const float*)d_in[4];
    const float* wg_in  = (const float*)d_in[5];
    const float* bg_in  = (const float*)d_in[6];
    const float* W_out  = (const float*)d_in[7];
    const float* b_out  = (const float*)d_in[8];
    const float* wg_out = (const float*)d_in[9];
    const float* bg_out = (const float*)d_in[10];
    float* out = (float*)d_out;

    if (ws_size >= WS_NEED) {
        unsigned short*      xbf = (unsigned short*)((char*)d_ws + XBF_OFF);
        unsigned long long*  rmp = (unsigned long long*)((char*)d_ws + RM_OFF);
        unsigned long long*  cmp = (unsigned long long*)((char*)d_ws + CM_OFF);
        hipLaunchKernelGGL(xpose_kernel, dim3(8, 32), dim3(256), 0, stream, X, xbf);
        hipLaunchKernelGGL(mask_kernel, dim3(2048), dim3(256), 0, stream, adj, rmp, cmp);
        hipLaunchKernelGGL(rfgcn_main, dim3(Ssz / TI, Bsz), dim3(512), 0, stream,
                           X, xbf, rmp, cmp, nw, W_in, b_in, wg_in, bg_in,
                           W_out, b_out, wg_out, bg_out, out);
    } else {
        hipLaunchKernelGGL(rfgcn_fallback, dim3(Ssz / TI, Bsz), dim3(512), 0, stream,
                           X, adj, nw, W_in, b_in, wg_in, bg_in,
                           W_out, b_out, wg_out, bg_out, out);
    }
}

// Round 18
// 105.678 us; speedup vs baseline: 1.0290x; 1.0219x over previous
//
#include <hip/hip_runtime.h>
#include <math.h>

typedef short short8 __attribute__((ext_vector_type(8)));
typedef float f32x4  __attribute__((ext_vector_type(4)));

constexpr int Ssz = 512, Dsz = 64, Lsz = 4, Bsz = 32;
constexpr int TI = 32, TJ = 64;

// ---- workspace layout ----
constexpr size_t XBF_OFF = 0;                          // [B][64 d][512 s] bf16 = 2 MB
constexpr size_t RM_OFF  = 2u  * 1024 * 1024;          // 4 MB u64 row-masks (adj[i][j])
constexpr size_t CM_OFF  = 6u  * 1024 * 1024;          // 4 MB u64 col-masks (adj[j][i])
constexpr size_t Y_OFF   = 10u * 1024 * 1024;          // [8 dirl][B][512][64] f32 = 32 MB
constexpr size_t D_OFF   = 42u * 1024 * 1024;          // [8 dirl][B][512] f32 = 512 KB
constexpr size_t WS_NEED = D_OFF + 512u * 1024;

// ---- epilogue LDS (floats) ----
constexpr int YBs = 69;
constexpr int YB_f = 0;                    // [32][69]
constexpr int WBs = 68;
constexpr int WB_f = YB_f + 32 * YBs;      // [64][68]
constexpr int DG_f = WB_f + 64 * WBs;      // [32]
constexpr int WG_f = DG_f + 32;            // [64]
constexpr int BB_f = WG_f + 64;            // [64]
constexpr int EPI_FLOATS = BB_f + 64;      // 26880 B

__device__ __forceinline__ unsigned short f2bf(float x) {
    union { float f; unsigned u; } v; v.f = x;
    unsigned r = v.u + 0x7FFFu + ((v.u >> 16) & 1u);   // RNE
    return (unsigned short)(r >> 16);
}

// ============ P1: X [B][S][D] f32 -> Xbf^T [B][D][S] bf16 (verified) ============
__global__ __launch_bounds__(256)
void xpose_kernel(const float* __restrict__ X, unsigned short* __restrict__ xbf)
{
    __shared__ unsigned short t[64][66];
    const int b = blockIdx.y, s0 = blockIdx.x * 64;
    const int tid = threadIdx.x;
    const int c = tid & 63, r4 = tid >> 6;
    const float* Xb = X + (size_t)b * Ssz * Dsz;
#pragma unroll
    for (int k = 0; k < 16; ++k) {
        const int s = r4 + 4 * k;
        t[s][c] = f2bf(Xb[(size_t)(s0 + s) * Dsz + c]);
    }
    __syncthreads();
    unsigned short* o = xbf + (size_t)b * Dsz * Ssz;
#pragma unroll
    for (int k = 0; k < 16; ++k) {
        const int d = r4 + 4 * k;
        o[(size_t)d * Ssz + s0 + c] = t[c][d];
    }
}

// ============ P2: adjacency -> bitmasks (verified) ============
__global__ __launch_bounds__(256)
void mask_kernel(const int* __restrict__ adj,
                 unsigned long long* __restrict__ rm,
                 unsigned long long* __restrict__ cm)
{
    const int tid  = threadIdx.x;
    const int lane = tid & 63;
    const int wt   = blockIdx.x * 4 + (tid >> 6);
    const int lb   = wt >> 6;
    const int rem  = wt & 63;
    const int r1t  = (rem >> 3) * 64;
    const int r2t  = (rem & 7) * 64;
    const int* A = adj + (size_t)lb * Ssz * Ssz;

    unsigned long long c = 0ull, rmine = 0ull;
#pragma unroll 4
    for (int j = 0; j < 64; ++j) {
        const int a = A[(size_t)(r1t + j) * Ssz + r2t + lane];
        const unsigned long long bal = __ballot(a != 0);
        if (lane == j) rmine = bal;
        c |= ((unsigned long long)(a != 0)) << j;
    }
    rm[((size_t)lb * 8 + (r2t >> 6)) * 512 + r1t + lane] = rmine;
    cm[((size_t)lb * 8 + (r1t >> 6)) * 512 + r2t + lane] = c;
}

// ============ A: aggregation only — 1 wave/block, no LDS, no barriers ============
__global__ __launch_bounds__(64, 4)
void agg_kernel(const unsigned short* __restrict__ xbf,
                const unsigned long long* __restrict__ rm,
                const unsigned long long* __restrict__ cm,
                float* __restrict__ Yws, float* __restrict__ Dws)
{
    const int ix   = blockIdx.x;            // i-tile 0..15
    const int b    = blockIdx.y;            // batch
    const int dirl = blockIdx.z;            // 0..7 = (dir, label)
    const int dir  = dirl & 1, wl = dirl >> 1;
    const int lane = threadIdx.x;
    const int lm   = lane & 15;
    const int lg   = lane >> 4;
    const int i0   = ix * TI;

    f32x4 acc[2][4];
    f32x4 dacc[2];
#pragma unroll
    for (int rt = 0; rt < 2; ++rt) {
#pragma unroll
        for (int nt = 0; nt < 4; ++nt) acc[rt][nt] = (f32x4){0.f, 0.f, 0.f, 0.f};
        dacc[rt] = (f32x4){0.f, 0.f, 0.f, 0.f};
    }
    const short8 ones = {(short)0x3F80, (short)0x3F80, (short)0x3F80, (short)0x3F80,
                         (short)0x3F80, (short)0x3F80, (short)0x3F80, (short)0x3F80};

    const unsigned long long* Mb = (dir ? rm : cm) + (size_t)(wl * Bsz + b) * 8 * 512;
    const unsigned short* xp0 = xbf + (size_t)b * Dsz * Ssz;

    for (int jc = 0; jc < 8; ++jc) {
        const unsigned long long m0 = Mb[(size_t)jc * 512 + i0 + lm];
        const unsigned long long m1 = Mb[(size_t)jc * 512 + i0 + 16 + lm];
        const unsigned short* xp = xp0 + jc * 64;
#pragma unroll
        for (int ks = 0; ks < 2; ++ks) {
            short8 bh[4];
#pragma unroll
            for (int nt = 0; nt < 4; ++nt)
                bh[nt] = *(const short8*)(xp + (size_t)(16 * nt + lm) * Ssz + 8 * (4 * ks + lg));
#pragma unroll
            for (int rt = 0; rt < 2; ++rt) {
                const unsigned bytev = (unsigned)((rt ? m1 : m0) >> (32 * ks + 8 * lg)) & 0xFFu;
                short8 af;
#pragma unroll
                for (int jj = 0; jj < 8; ++jj)
                    af[jj] = ((bytev >> jj) & 1u) ? (short)0x3F80 : (short)0;
#pragma unroll
                for (int nt = 0; nt < 4; ++nt)
                    acc[rt][nt] = __builtin_amdgcn_mfma_f32_16x16x32_bf16(af, bh[nt], acc[rt][nt], 0, 0, 0);
                dacc[rt] = __builtin_amdgcn_mfma_f32_16x16x32_bf16(af, ones, dacc[rt], 0, 0, 0);
            }
        }
    }

    // write Y[dirl][b][i][e] f32 and deg
    float* Yp = Yws + ((size_t)dirl * Bsz + b) * Ssz * Dsz;
#pragma unroll
    for (int rt = 0; rt < 2; ++rt)
#pragma unroll
        for (int nt = 0; nt < 4; ++nt)
#pragma unroll
            for (int r = 0; r < 4; ++r)
                Yp[(size_t)(i0 + 16 * rt + 4 * lg + r) * Dsz + 16 * nt + lm] = acc[rt][nt][r];
    if (lm == 0) {
        float* Dp = Dws + ((size_t)dirl * Bsz + b) * Ssz;
#pragma unroll
        for (int rt = 0; rt < 2; ++rt)
#pragma unroll
            for (int r = 0; r < 4; ++r)
                Dp[i0 + 16 * rt + 4 * lg + r] = dacc[rt][r];
    }
}

// ============ B: epilogue only — r8/r12-verified VALU transform ============
__global__ __launch_bounds__(512, 4)
void epi_kernel(const float* __restrict__ X,
                const float* __restrict__ Yws, const float* __restrict__ Dws,
                const float* __restrict__ nw,
                const float* __restrict__ W_in,  const float* __restrict__ b_in,
                const float* __restrict__ wg_in, const float* __restrict__ bg_in,
                const float* __restrict__ W_out, const float* __restrict__ b_out,
                const float* __restrict__ wg_out,const float* __restrict__ bg_out,
                float* __restrict__ out)
{
    __shared__ float smf[EPI_FLOATS];
    const int tid = threadIdx.x;
    const int b   = blockIdx.y;
    const int i0  = blockIdx.x * TI;
    const int ei  = tid & 31;
    const int ecg = tid >> 5;
    float fin[4];
#pragma unroll
    for (int q = 0; q < 4; ++q) fin[q] = 0.f;

#pragma unroll
    for (int l = 0; l < Lsz; ++l) {
#pragma unroll
        for (int d2 = 0; d2 < 2; ++d2) {
            if (l + d2) __syncthreads();
            // stage Y slice [32][64] from ws (coalesced float4/thread)
            {
                const float* Yp = Yws + ((size_t)(2 * l + d2) * Bsz + b) * Ssz * Dsz
                                + (size_t)i0 * Dsz;
                const float4 yv = *(const float4*)&Yp[tid * 4];
                const int row = tid >> 4, col = (tid & 15) * 4;
                smf[YB_f + row * YBs + col + 0] = yv.x;
                smf[YB_f + row * YBs + col + 1] = yv.y;
                smf[YB_f + row * YBs + col + 2] = yv.z;
                smf[YB_f + row * YBs + col + 3] = yv.w;
            }
            if (tid < 32)
                smf[DG_f + tid] = Dws[((size_t)(2 * l + d2) * Bsz + b) * Ssz + i0 + tid];
            // stage W
            const float* Wp = (d2 ? W_out : W_in) + l * Dsz * Dsz;
            {
                const int r = tid >> 3, c8 = tid & 7;
                *(float4*)&smf[WB_f + r * WBs + 8 * c8]     = *(const float4*)&Wp[r * Dsz + 8 * c8];
                *(float4*)&smf[WB_f + r * WBs + 8 * c8 + 4] = *(const float4*)&Wp[r * Dsz + 8 * c8 + 4];
            }
            const float* wgp = (d2 ? wg_out : wg_in) + l * Dsz;
            const float* bp  = (d2 ? b_out  : b_in)  + l * Dsz;
            if (tid >= 384 && tid < 448)      smf[WG_f + tid - 384] = wgp[tid - 384];
            else if (tid >= 448)              smf[BB_f + tid - 448] = bp[tid - 448];
            const float bgs = (d2 ? bg_out : bg_in)[l];
            __syncthreads();

            const float dg = smf[DG_f + ei];
            float tq[4];
#pragma unroll
            for (int q = 0; q < 4; ++q) tq[q] = dg * smf[BB_f + 4 * ecg + q];
            float gate = dg * bgs;
#pragma unroll 4
            for (int e = 0; e < 64; ++e) {
                const float yv = smf[YB_f + ei * YBs + e];
                gate += yv * smf[WG_f + e];
#pragma unroll
                for (int q = 0; q < 4; ++q) tq[q] += yv * smf[WB_f + e * WBs + 4 * ecg + q];
            }
            const float sg = 1.f / (1.f + expf(-gate));
#pragma unroll
            for (int q = 0; q < 4; ++q) fin[q] += tq[q] * sg;
        }
    }

    const float inv = 1.f / (3.f * nw[b]);
    const float* Xb = X + (size_t)b * Ssz * Dsz;
    const float4 xr = *(const float4*)&Xb[(size_t)(i0 + ei) * Dsz + 4 * ecg];
    float4 o;
    o.x = (xr.x + fin[0]) * inv;
    o.y = (xr.y + fin[1]) * inv;
    o.z = (xr.z + fin[2]) * inv;
    o.w = (xr.w + fin[3]) * inv;
    *(float4*)(out + ((size_t)b * Ssz + i0 + ei) * Dsz + 4 * ecg) = o;
}

// ============ fallback (r12 kernel, 76 us verified) ============
constexpr int XTb[2] = {0, 4096};
constexpr int FB_SMEM = EPI_FLOATS * 4;

__global__ __launch_bounds__(512, 4)
void rfgcn_fallback(const float* __restrict__ X, const int* __restrict__ adj,
                    const float* __restrict__ nw,
                    const float* __restrict__ W_in,  const float* __restrict__ b_in,
                    const float* __restrict__ wg_in, const float* __restrict__ bg_in,
                    const float* __restrict__ W_out, const float* __restrict__ b_out,
                    const float* __restrict__ wg_out,const float* __restrict__ bg_out,
                    float* __restrict__ out)
{
    __shared__ __align__(16) char smem[FB_SMEM];
    short* sm16 = (short*)smem;
    float* smf  = (float*)smem;

    const int tid  = threadIdx.x;
    const int b    = blockIdx.y;
    const int i0   = blockIdx.x * TI;
    const int w    = tid >> 6;
    const int lane = tid & 63;
    const int dir  = w & 1;
    const int wl   = w >> 1;
    const int lm   = lane & 15;
    const int lg   = lane >> 4;

    f32x4 acc[2][4];
    f32x4 dacc[2];
#pragma unroll
    for (int rt = 0; rt < 2; ++rt) {
#pragma unroll
        for (int nt = 0; nt < 4; ++nt) acc[rt][nt] = (f32x4){0.f, 0.f, 0.f, 0.f};
        dacc[rt] = (f32x4){0.f, 0.f, 0.f, 0.f};
    }
    const short8 ones = {(short)0x3F80, (short)0x3F80, (short)0x3F80, (short)0x3F80,
                         (short)0x3F80, (short)0x3F80, (short)0x3F80, (short)0x3F80};

    const float* Xb = X + (size_t)b * Ssz * Dsz;
    const int*   Ab = adj + ((size_t)wl * Bsz + b) * Ssz * Ssz;

    float xv[8];
    int   aR[32];

#define ADJ_LOAD(T)                                                              \
    {                                                                            \
        const int J0 = (T) * TJ;                                                 \
        if (dir == 0) {                                                          \
            _Pragma("unroll")                                                    \
            for (int rt = 0; rt < 2; ++rt)                                       \
                _Pragma("unroll")                                                \
                for (int ks = 0; ks < 2; ++ks)                                   \
                    _Pragma("unroll")                                            \
                    for (int j = 0; j < 8; ++j)                                  \
                        aR[rt * 16 + ks * 8 + j] =                               \
                            Ab[(size_t)(J0 + 32 * ks + 8 * lg + j) * Ssz + i0 + 16 * rt + lm]; \
        } else {                                                                 \
            _Pragma("unroll")                                                    \
            for (int rt = 0; rt < 2; ++rt)                                       \
                _Pragma("unroll")                                                \
                for (int ks = 0; ks < 2; ++ks) {                                 \
                    const int* p = &Ab[(size_t)(i0 + 16 * rt + lm) * Ssz + J0 + 32 * ks + 8 * lg]; \
                    const int4 q0 = *(const int4*)p;                             \
                    const int4 q1 = *(const int4*)(p + 4);                       \
                    aR[rt * 16 + ks * 8 + 0] = q0.x; aR[rt * 16 + ks * 8 + 1] = q0.y; \
                    aR[rt * 16 + ks * 8 + 2] = q0.z; aR[rt * 16 + ks * 8 + 3] = q0.w; \
                    aR[rt * 16 + ks * 8 + 4] = q1.x; aR[rt * 16 + ks * 8 + 5] = q1.y; \
                    aR[rt * 16 + ks * 8 + 6] = q1.z; aR[rt * 16 + ks * 8 + 7] = q1.w; \
                }                                                                \
        }                                                                        \
    }
#define X_LOAD(T)                                                                \
    {                                                                            \
        const int J0 = (T) * TJ;                                                 \
        _Pragma("unroll")                                                        \
        for (int s = 0; s < 8; ++s) xv[s] = Xb[(size_t)(J0 + 8 * w + s) * Dsz + lane]; \
    }
#define X_WRITE(BUF)                                                             \
    {                                                                            \
        short8 hi;                                                               \
        _Pragma("unroll")                                                        \
        for (int s = 0; s < 8; ++s) hi[s] = (short)f2bf(xv[s]);                  \
        const int g = w ^ (lane & 7);                                            \
        *(short8*)(sm16 + XTb[BUF] + lane * 64 + g * 8) = hi;                    \
    }

    X_LOAD(0)
    X_WRITE(0)
    ADJ_LOAD(0)
    X_LOAD(1)
    __syncthreads();

    for (int t = 0; t < 8; ++t) {
        const int cur = t & 1;
        short8 af[2][2];
#pragma unroll
        for (int rt = 0; rt < 2; ++rt)
#pragma unroll
            for (int ks = 0; ks < 2; ++ks)
#pragma unroll
                for (int j = 0; j < 8; ++j)
                    af[rt][ks][j] = aR[rt * 16 + ks * 8 + j] ? (short)0x3F80 : (short)0;

        if (t < 7) ADJ_LOAD(t + 1)
        if (t < 7) X_WRITE(cur ^ 1)
        if (t < 6) X_LOAD(t + 2)

#pragma unroll
        for (int ks = 0; ks < 2; ++ks) {
            short8 bh[4];
#pragma unroll
            for (int nt = 0; nt < 4; ++nt) {
                const int d = nt * 16 + lm;
                const int g = (4 * ks + lg) ^ (d & 7);
                bh[nt] = *(const short8*)(sm16 + XTb[cur] + d * 64 + g * 8);
            }
#pragma unroll
            for (int rt = 0; rt < 2; ++rt) {
#pragma unroll
                for (int nt = 0; nt < 4; ++nt)
                    acc[rt][nt] = __builtin_amdgcn_mfma_f32_16x16x32_bf16(af[rt][ks], bh[nt], acc[rt][nt], 0, 0, 0);
                dacc[rt] = __builtin_amdgcn_mfma_f32_16x16x32_bf16(af[rt][ks], ones, dacc[rt], 0, 0, 0);
            }
        }
        __syncthreads();
    }
#undef ADJ_LOAD
#undef X_LOAD
#undef X_WRITE

    const int ei  = tid & 31;
    const int ecg = tid >> 5;
    float fin[4];
#pragma unroll
    for (int q = 0; q < 4; ++q) fin[q] = 0.f;

#pragma unroll
    for (int l = 0; l < Lsz; ++l) {
#pragma unroll
        for (int d2 = 0; d2 < 2; ++d2) {
            if (l + d2) __syncthreads();
            if (dir == d2 && wl == l) {
#pragma unroll
                for (int rt = 0; rt < 2; ++rt)
#pragma unroll
                    for (int nt = 0; nt < 4; ++nt)
#pragma unroll
                        for (int r = 0; r < 4; ++r)
                            smf[YB_f + (16 * rt + 4 * lg + r) * YBs + nt * 16 + lm] = acc[rt][nt][r];
                if (lm == 0)
#pragma unroll
                    for (int rt = 0; rt < 2; ++rt)
#pragma unroll
                        for (int r = 0; r < 4; ++r)
                            smf[DG_f + 16 * rt + 4 * lg + r] = dacc[rt][r];
            }
            const float* Wp = (d2 ? W_out : W_in) + l * Dsz * Dsz;
            {
                const int r = tid >> 3, c8 = tid & 7;
                *(float4*)&smf[WB_f + r * WBs + 8 * c8]     = *(const float4*)&Wp[r * Dsz + 8 * c8];
                *(float4*)&smf[WB_f + r * WBs + 8 * c8 + 4] = *(const float4*)&Wp[r * Dsz + 8 * c8 + 4];
            }
            const float* wgp = (d2 ? wg_out : wg_in) + l * Dsz;
            const float* bp  = (d2 ? b_out  : b_in)  + l * Dsz;
            if (tid < 64)        smf[WG_f + tid]      = wgp[tid];
            else if (tid < 128)  smf[BB_f + tid - 64] = bp[tid - 64];
            const float bgs = (d2 ? bg_out : bg_in)[l];
            __syncthreads();

            const float dg = smf[DG_f + ei];
            float tq[4];
#pragma unroll
            for (int q = 0; q < 4; ++q) tq[q] = dg * smf[BB_f + 4 * ecg + q];
            float gate = dg * bgs;
#pragma unroll 4
            for (int e = 0; e < 64; ++e) {
                const float yv = smf[YB_f + ei * YBs + e];
                gate += yv * smf[WG_f + e];
#pragma unroll
                for (int q = 0; q < 4; ++q) tq[q] += yv * smf[WB_f + e * WBs + 4 * ecg + q];
            }
            const float sg = 1.f / (1.f + expf(-gate));
#pragma unroll
            for (int q = 0; q < 4; ++q) fin[q] += tq[q] * sg;
        }
    }

    const float inv = 1.f / (3.f * nw[b]);
    const float4 xr = *(const float4*)&Xb[(size_t)(i0 + ei) * Dsz + 4 * ecg];
    float4 o;
    o.x = (xr.x + fin[0]) * inv;
    o.y = (xr.y + fin[1]) * inv;
    o.z = (xr.z + fin[2]) * inv;
    o.w = (xr.w + fin[3]) * inv;
    *(float4*)(out + ((size_t)b * Ssz + i0 + ei) * Dsz + 4 * ecg) = o;
}

extern "C" void kernel_launch(void* const* d_in, const int* in_sizes, int n_in,
                              void* d_out, int out_size, void* d_ws, size_t ws_size,
                              hipStream_t stream)
{
    const float* X      = (const float*)d_in[0];
    const int*   adj    = (const int*)  d_in[1];
    const float* nw     = (const float*)d_in[2];
    const float* W_in   = (const float*)d_in[3];
    const float* b_in   = (const float*)d_in[4];
    const float* wg_in  = (const float*)d_in[5];
    const float* bg_in  = (const float*)d_in[6];
    const float* W_out  = (const float*)d_in[7];
    const float* b_out  = (const float*)d_in[8];
    const float* wg_out = (const float*)d_in[9];
    const float* bg_out = (const float*)d_in[10];
    float* out = (float*)d_out;

    if (ws_size >= WS_NEED) {
        unsigned short*     xbf = (unsigned short*)((char*)d_ws + XBF_OFF);
        unsigned long long* rmp = (unsigned long long*)((char*)d_ws + RM_OFF);
        unsigned long long* cmp = (unsigned long long*)((char*)d_ws + CM_OFF);
        float*              Yws = (float*)((char*)d_ws + Y_OFF);
        float*              Dws = (float*)((char*)d_ws + D_OFF);
        hipLaunchKernelGGL(xpose_kernel, dim3(8, 32), dim3(256), 0, stream, X, xbf);
        hipLaunchKernelGGL(mask_kernel, dim3(2048), dim3(256), 0, stream, adj, rmp, cmp);
        hipLaunchKernelGGL(agg_kernel, dim3(16, 32, 8), dim3(64), 0, stream,
                           xbf, rmp, cmp, Yws, Dws);
        hipLaunchKernelGGL(epi_kernel, dim3(16, 32), dim3(512), 0, stream,
                           X, Yws, Dws, nw, W_in, b_in, wg_in, bg_in,
                           W_out, b_out, wg_out, bg_out, out);
    } else {
        hipLaunchKernelGGL(rfgcn_fallback, dim3(Ssz / TI, Bsz), dim3(512), 0, stream,
                           X, adj, nw, W_in, b_in, wg_in, bg_in,
                           W_out, b_out, wg_out, bg_out, out);
    }
}

// Round 19
// 86.863 us; speedup vs baseline: 1.2519x; 1.2166x over previous
//
#include <hip/hip_runtime.h>
#include <math.h>

typedef short short8 __attribute__((ext_vector_type(8)));
typedef float f32x4  __attribute__((ext_vector_type(4)));

constexpr int Ssz = 512, Dsz = 64, Lsz = 4, Bsz = 32;
constexpr int TI = 32, TJ = 64;

// LDS: X^T resident [64 d][512 s] bf16 = 65536 B (2 blocks/CU; forces 128-VGPR budget).
// Granule (8-short = 16B) XOR swizzle within each aligned group of 8 granules:
//   stored_g = (g & ~7) | ((g & 7) ^ (d & 7))  -> conflict-free b128 frag reads (r12-verified pattern).
constexpr int SMEM_SHORTS = 64 * 512;

// epilogue overlay (floats, aliases X region after the epilogue barrier; 26880 B < 64 KB)
constexpr int YBs = 69;
constexpr int YB_f = 0;                    // [32][69]
constexpr int WBs = 68;
constexpr int WB_f = YB_f + 32 * YBs;      // [64][68]
constexpr int DG_f = WB_f + 64 * WBs;      // [32]
constexpr int WG_f = DG_f + 32;            // [64]
constexpr int BB_f = WG_f + 64;            // [64]

__device__ __forceinline__ unsigned short f2bf(float x) {
    union { float f; unsigned u; } v; v.f = x;
    unsigned r = v.u + 0x7FFFu + ((v.u >> 16) & 1u);   // RNE
    return (unsigned short)(r >> 16);
}

__global__ __launch_bounds__(512, 2)
void rfgcn_xres(const float* __restrict__ X,      // [B][S][D]
                const int*   __restrict__ adj,    // [L][B][S][S]
                const float* __restrict__ nw,
                const float* __restrict__ W_in,  const float* __restrict__ b_in,
                const float* __restrict__ wg_in, const float* __restrict__ bg_in,
                const float* __restrict__ W_out, const float* __restrict__ b_out,
                const float* __restrict__ wg_out,const float* __restrict__ bg_out,
                float* __restrict__ out)
{
    __shared__ __align__(16) short sm16[SMEM_SHORTS];
    float* smf = (float*)sm16;

    const int tid  = threadIdx.x;
    const int b    = blockIdx.y;
    const int i0   = blockIdx.x * TI;
    const int w    = tid >> 6;       // wave 0..7
    const int lane = tid & 63;
    const int dir  = w & 1;          // 0 = in (A^T), 1 = out (A)
    const int wl   = w >> 1;         // label 0..3
    const int lm   = lane & 15;
    const int lg   = lane >> 4;      // k-group 0..3

    const float* Xb = X + (size_t)b * Ssz * Dsz;
    const int*   Ab = adj + ((size_t)wl * Bsz + b) * Ssz * Ssz;

    // ---- stage X^T RESIDENT (once): thread owns row d=lane, s-block (tid>>6)*64 ----
    {
        const int d  = lane;
        const int sb = (tid >> 6) * 64;
#pragma unroll
        for (int m = 0; m < 8; ++m) {
            float xs[8];
#pragma unroll
            for (int q = 0; q < 8; ++q)
                xs[q] = Xb[(size_t)(sb + m * 8 + q) * Dsz + d];   // coalesced 256B rows
            short8 hv;
#pragma unroll
            for (int q = 0; q < 8; ++q) hv[q] = (short)f2bf(xs[q]);
            const int gf = (sb >> 3) + m;                          // logical granule 0..63
            const int gs = (gf & ~7) | ((gf & 7) ^ (d & 7));       // swizzled
            *(short8*)(sm16 + d * 512 + gs * 8) = hv;
        }
    }

    f32x4 acc[2][4];
    f32x4 dacc[2];
#pragma unroll
    for (int rt = 0; rt < 2; ++rt) {
#pragma unroll
        for (int nt = 0; nt < 4; ++nt) acc[rt][nt] = (f32x4){0.f, 0.f, 0.f, 0.f};
        dacc[rt] = (f32x4){0.f, 0.f, 0.f, 0.f};
    }
    const short8 ones = {(short)0x3F80, (short)0x3F80, (short)0x3F80, (short)0x3F80,
                         (short)0x3F80, (short)0x3F80, (short)0x3F80, (short)0x3F80};

    int aR[32];   // adjacency fragment regs (1 chunk ahead)

#define ADJ_LOAD(T)                                                              \
    {                                                                            \
        const int J0 = (T) * TJ;                                                 \
        if (dir == 0) {                                                          \
            _Pragma("unroll")                                                    \
            for (int rt = 0; rt < 2; ++rt)                                       \
                _Pragma("unroll")                                                \
                for (int ks = 0; ks < 2; ++ks)                                   \
                    _Pragma("unroll")                                            \
                    for (int j = 0; j < 8; ++j)                                  \
                        aR[rt * 16 + ks * 8 + j] =                               \
                            Ab[(size_t)(J0 + 32 * ks + 8 * lg + j) * Ssz + i0 + 16 * rt + lm]; \
        } else {                                                                 \
            _Pragma("unroll")                                                    \
            for (int rt = 0; rt < 2; ++rt)                                       \
                _Pragma("unroll")                                                \
                for (int ks = 0; ks < 2; ++ks) {                                 \
                    const int* p = &Ab[(size_t)(i0 + 16 * rt + lm) * Ssz + J0 + 32 * ks + 8 * lg]; \
                    const int4 q0 = *(const int4*)p;                             \
                    const int4 q1 = *(const int4*)(p + 4);                       \
                    aR[rt * 16 + ks * 8 + 0] = q0.x; aR[rt * 16 + ks * 8 + 1] = q0.y; \
                    aR[rt * 16 + ks * 8 + 2] = q0.z; aR[rt * 16 + ks * 8 + 3] = q0.w; \
                    aR[rt * 16 + ks * 8 + 4] = q1.x; aR[rt * 16 + ks * 8 + 5] = q1.y; \
                    aR[rt * 16 + ks * 8 + 6] = q1.z; aR[rt * 16 + ks * 8 + 7] = q1.w; \
                }                                                                \
        }                                                                        \
    }

    ADJ_LOAD(0)          // in flight while X staging drains
    __syncthreads();     // X^T resident & visible

    // ---- main loop: ZERO barriers, ZERO LDS writes — waves free-run & de-phase ----
    for (int t = 0; t < 8; ++t) {
        short8 af[2][2];
#pragma unroll
        for (int rt = 0; rt < 2; ++rt)
#pragma unroll
            for (int ks = 0; ks < 2; ++ks)
#pragma unroll
                for (int j = 0; j < 8; ++j)
                    af[rt][ks][j] = aR[rt * 16 + ks * 8 + j] ? (short)0x3F80 : (short)0;

        if (t < 7) ADJ_LOAD(t + 1)      // next chunk in flight under this chunk's MFMAs

#pragma unroll
        for (int ks = 0; ks < 2; ++ks) {
            short8 bh[4];
#pragma unroll
            for (int nt = 0; nt < 4; ++nt) {
                const int d  = nt * 16 + lm;
                const int gs = t * 8 + ((4 * ks + lg) ^ (d & 7));   // swizzled granule
                bh[nt] = *(const short8*)(sm16 + d * 512 + gs * 8);
            }
#pragma unroll
            for (int rt = 0; rt < 2; ++rt) {
#pragma unroll
                for (int nt = 0; nt < 4; ++nt)
                    acc[rt][nt] = __builtin_amdgcn_mfma_f32_16x16x32_bf16(af[rt][ks], bh[nt], acc[rt][nt], 0, 0, 0);
                dacc[rt] = __builtin_amdgcn_mfma_f32_16x16x32_bf16(af[rt][ks], ones, dacc[rt], 0, 0, 0);
            }
        }
    }
#undef ADJ_LOAD

    // ======== epilogue (r12-verified): t = Y*W + deg*b; gate = Y*wg + deg*bg
    const int ei  = tid & 31;
    const int ecg = tid >> 5;
    float fin[4];
#pragma unroll
    for (int q = 0; q < 4; ++q) fin[q] = 0.f;

#pragma unroll
    for (int l = 0; l < Lsz; ++l) {
#pragma unroll
        for (int d2 = 0; d2 < 2; ++d2) {
            __syncthreads();   // ALL waves past main (first pass) / prev consumers done
            if (dir == d2 && wl == l) {   // owning wave writes its full Y (32 rows)
#pragma unroll
                for (int rt = 0; rt < 2; ++rt)
#pragma unroll
                    for (int nt = 0; nt < 4; ++nt)
#pragma unroll
                        for (int r = 0; r < 4; ++r)
                            smf[YB_f + (16 * rt + 4 * lg + r) * YBs + nt * 16 + lm] = acc[rt][nt][r];
                if (lm == 0)
#pragma unroll
                    for (int rt = 0; rt < 2; ++rt)
#pragma unroll
                        for (int r = 0; r < 4; ++r)
                            smf[DG_f + 16 * rt + 4 * lg + r] = dacc[rt][r];
            }
            // stage W (all threads, coalesced float4)
            const float* Wp = (d2 ? W_out : W_in) + l * Dsz * Dsz;
            {
                const int r = tid >> 3, c8 = tid & 7;
                *(float4*)&smf[WB_f + r * WBs + 8 * c8]     = *(const float4*)&Wp[r * Dsz + 8 * c8];
                *(float4*)&smf[WB_f + r * WBs + 8 * c8 + 4] = *(const float4*)&Wp[r * Dsz + 8 * c8 + 4];
            }
            const float* wgp = (d2 ? wg_out : wg_in) + l * Dsz;
            const float* bp  = (d2 ? b_out  : b_in)  + l * Dsz;
            if (tid < 64)        smf[WG_f + tid]      = wgp[tid];
            else if (tid < 128)  smf[BB_f + tid - 64] = bp[tid - 64];
            const float bgs = (d2 ? bg_out : bg_in)[l];
            __syncthreads();

            const float dg = smf[DG_f + ei];
            float tq[4];
#pragma unroll
            for (int q = 0; q < 4; ++q) tq[q] = dg * smf[BB_f + 4 * ecg + q];
            float gate = dg * bgs;
#pragma unroll 4
            for (int e = 0; e < 64; ++e) {
                const float yv = smf[YB_f + ei * YBs + e];
                gate += yv * smf[WG_f + e];
#pragma unroll
                for (int q = 0; q < 4; ++q) tq[q] += yv * smf[WB_f + e * WBs + 4 * ecg + q];
            }
            const float sg = 1.f / (1.f + expf(-gate));
#pragma unroll
            for (int q = 0; q < 4; ++q) fin[q] += tq[q] * sg;
        }
    }

    const float inv = 1.f / (3.f * nw[b]);
    const float4 xr = *(const float4*)&Xb[(size_t)(i0 + ei) * Dsz + 4 * ecg];
    float4 o;
    o.x = (xr.x + fin[0]) * inv;
    o.y = (xr.y + fin[1]) * inv;
    o.z = (xr.z + fin[2]) * inv;
    o.w = (xr.w + fin[3]) * inv;
    *(float4*)(out + ((size_t)b * Ssz + i0 + ei) * Dsz + 4 * ecg) = o;
}

extern "C" void kernel_launch(void* const* d_in, const int* in_sizes, int n_in,
                              void* d_out, int out_size, void* d_ws, size_t ws_size,
                              hipStream_t stream)
{
    const float* X      = (const float*)d_in[0];
    const int*   adj    = (const int*)  d_in[1];
    const float* nw     = (const float*)d_in[2];
    const float* W_in   = (const float*)d_in[3];
    const float* b_in   = (const float*)d_in[4];
    const float* wg_in  = (const float*)d_in[5];
    const float* bg_in  = (const float*)d_in[6];
    const float* W_out  = (const float*)d_in[7];
    const float* b_out  = (const float*)d_in[8];
    const float* wg_out = (const float*)d_in[9];
    const float* bg_out = (const float*)d_in[10];
    float* out = (float*)d_out;

    dim3 grid(Ssz / TI, Bsz);   // (16, 32) = 512 blocks -> 2/CU
    dim3 block(512);
    hipLaunchKernelGGL(rfgcn_xres, grid, block, 0, stream,
                       X, adj, nw, W_in, b_in, wg_in, bg_in,
                       W_out, b_out, wg_out, bg_out, out);
}

// Round 20
// 85.330 us; speedup vs baseline: 1.2744x; 1.0180x over previous
//
#include <hip/hip_runtime.h>
#include <math.h>

typedef short short8 __attribute__((ext_vector_type(8)));
typedef float f32x4  __attribute__((ext_vector_type(4)));

constexpr int Ssz = 512, Dsz = 64, Lsz = 4, Bsz = 32;
constexpr int TI = 32, TJ = 64;

// main-loop LDS: X^T double-buffered [2][64][64] bf16 (r12-verified, 16 KB)
constexpr int XTb[2] = {0, 4096};                 // short offsets

// epilogue overlay (floats): pair-indexed (q = dir), pass = label
constexpr int YST  = 32 * 69;                     // Y slice stride (69 = 5 mod 32, conflict-free)
constexpr int YB_f = 0;                           // 2 x [32][69]
constexpr int WST  = 64 * 68;
constexpr int WB_f = YB_f + 2 * YST;              // 2 x [64][68]
constexpr int DG_f = WB_f + 2 * WST;              // 2 x [32]
constexpr int WG_f = DG_f + 2 * 32;               // 2 x [64]
constexpr int BB_f = WG_f + 2 * 64;               // 2 x [64]
constexpr int EPI_FLOATS = BB_f + 2 * 64;         // 13440 floats = 53760 B
constexpr int FXB  = 0;                           // final cross-half exchange (reuses Y region)
constexpr int SMEM_BYTES = EPI_FLOATS * 4;        // 53760 B -> 2 blocks/CU

__device__ __forceinline__ unsigned short f2bf(float x) {
    union { float f; unsigned u; } v; v.f = x;
    unsigned r = v.u + 0x7FFFu + ((v.u >> 16) & 1u);   // RNE
    return (unsigned short)(r >> 16);
}

__global__ __launch_bounds__(512, 2)
void rfgcn_mfma(const float* __restrict__ X,      // [B][S][D]
                const int*   __restrict__ adj,    // [L][B][S][S]
                const float* __restrict__ nw,
                const float* __restrict__ W_in,  const float* __restrict__ b_in,
                const float* __restrict__ wg_in, const float* __restrict__ bg_in,
                const float* __restrict__ W_out, const float* __restrict__ b_out,
                const float* __restrict__ wg_out,const float* __restrict__ bg_out,
                float* __restrict__ out)
{
    __shared__ __align__(16) char smem[SMEM_BYTES];
    short* sm16 = (short*)smem;
    float* smf  = (float*)smem;

    const int tid  = threadIdx.x;
    const int b    = blockIdx.y;
    const int i0   = blockIdx.x * TI;
    const int w    = tid >> 6;       // wave 0..7
    const int lane = tid & 63;
    const int dir  = w & 1;          // 0 = in (A^T), 1 = out (A)
    const int wl   = w >> 1;         // label 0..3 owned by this wave
    const int lm   = lane & 15;
    const int lg   = lane >> 4;      // k-group 0..3

    f32x4 acc[2][4];                 // [row-tile rt][e-tile nt]
    f32x4 dacc[2];
#pragma unroll
    for (int rt = 0; rt < 2; ++rt) {
#pragma unroll
        for (int nt = 0; nt < 4; ++nt) acc[rt][nt] = (f32x4){0.f, 0.f, 0.f, 0.f};
        dacc[rt] = (f32x4){0.f, 0.f, 0.f, 0.f};
    }
    const short8 ones = {(short)0x3F80, (short)0x3F80, (short)0x3F80, (short)0x3F80,
                         (short)0x3F80, (short)0x3F80, (short)0x3F80, (short)0x3F80};

    const float* Xb = X + (size_t)b * Ssz * Dsz;
    const int*   Ab = adj + ((size_t)wl * Bsz + b) * Ssz * Ssz;

    float xv[8];     // X prefetch (chunk t+1)
    int   aR[32];    // adjacency fragment prefetch

#define ADJ_LOAD(T)                                                              \
    {                                                                            \
        const int J0 = (T) * TJ;                                                 \
        if (dir == 0) {                                                          \
            _Pragma("unroll")                                                    \
            for (int rt = 0; rt < 2; ++rt)                                       \
                _Pragma("unroll")                                                \
                for (int ks = 0; ks < 2; ++ks)                                   \
                    _Pragma("unroll")                                            \
                    for (int j = 0; j < 8; ++j)                                  \
                        aR[rt * 16 + ks * 8 + j] =                               \
                            Ab[(size_t)(J0 + 32 * ks + 8 * lg + j) * Ssz + i0 + 16 * rt + lm]; \
        } else {                                                                 \
            _Pragma("unroll")                                                    \
            for (int rt = 0; rt < 2; ++rt)                                       \
                _Pragma("unroll")                                                \
                for (int ks = 0; ks < 2; ++ks) {                                 \
                    const int* p = &Ab[(size_t)(i0 + 16 * rt + lm) * Ssz + J0 + 32 * ks + 8 * lg]; \
                    const int4 q0 = *(const int4*)p;                             \
                    const int4 q1 = *(const int4*)(p + 4);                       \
                    aR[rt * 16 + ks * 8 + 0] = q0.x; aR[rt * 16 + ks * 8 + 1] = q0.y; \
                    aR[rt * 16 + ks * 8 + 2] = q0.z; aR[rt * 16 + ks * 8 + 3] = q0.w; \
                    aR[rt * 16 + ks * 8 + 4] = q1.x; aR[rt * 16 + ks * 8 + 5] = q1.y; \
                    aR[rt * 16 + ks * 8 + 6] = q1.z; aR[rt * 16 + ks * 8 + 7] = q1.w; \
                }                                                                \
        }                                                                        \
    }
#define X_LOAD(T)                                                                \
    {                                                                            \
        const int J0 = (T) * TJ;                                                 \
        _Pragma("unroll")                                                        \
        for (int s = 0; s < 8; ++s) xv[s] = Xb[(size_t)(J0 + 8 * w + s) * Dsz + lane]; \
    }
#define X_WRITE(BUF)                                                             \
    {                                                                            \
        short8 hi;                                                               \
        _Pragma("unroll")                                                        \
        for (int s = 0; s < 8; ++s) hi[s] = (short)f2bf(xv[s]);                  \
        const int g = w ^ (lane & 7);                                            \
        *(short8*)(sm16 + XTb[BUF] + lane * 64 + g * 8) = hi;                    \
    }

    // ---- pipeline prologue (r12-verified)
    X_LOAD(0)
    X_WRITE(0)
    ADJ_LOAD(0)
    X_LOAD(1)
    __syncthreads();

    for (int t = 0; t < 8; ++t) {
        const int cur = t & 1;
        short8 af[2][2];
#pragma unroll
        for (int rt = 0; rt < 2; ++rt)
#pragma unroll
            for (int ks = 0; ks < 2; ++ks)
#pragma unroll
                for (int j = 0; j < 8; ++j)
                    af[rt][ks][j] = aR[rt * 16 + ks * 8 + j] ? (short)0x3F80 : (short)0;

        if (t < 7) ADJ_LOAD(t + 1)
        if (t < 7) X_WRITE(cur ^ 1)
        if (t < 6) X_LOAD(t + 2)

#pragma unroll
        for (int ks = 0; ks < 2; ++ks) {
            short8 bh[4];
#pragma unroll
            for (int nt = 0; nt < 4; ++nt) {
                const int d = nt * 16 + lm;
                const int g = (4 * ks + lg) ^ (d & 7);
                bh[nt] = *(const short8*)(sm16 + XTb[cur] + d * 64 + g * 8);
            }
#pragma unroll
            for (int rt = 0; rt < 2; ++rt) {
#pragma unroll
                for (int nt = 0; nt < 4; ++nt)
                    acc[rt][nt] = __builtin_amdgcn_mfma_f32_16x16x32_bf16(af[rt][ks], bh[nt], acc[rt][nt], 0, 0, 0);
                dacc[rt] = __builtin_amdgcn_mfma_f32_16x16x32_bf16(af[rt][ks], ones, dacc[rt], 0, 0, 0);
            }
        }
        __syncthreads();
    }
#undef ADJ_LOAD
#undef X_LOAD
#undef X_WRITE

    // ======== epilogue: pass p = label; half q = tid>>8 = direction; 4x2 register block
    const int q  = tid >> 8;          // 0,1 = dir handled by this half
    const int t2 = tid & 255;
    const int ec = t2 & 31;           // cols 2ec, 2ec+1
    const int er = t2 >> 5;           // rows 4er..4er+3
    float fin2[4][2];
#pragma unroll
    for (int r = 0; r < 4; ++r) { fin2[r][0] = 0.f; fin2[r][1] = 0.f; }

#pragma unroll
    for (int p = 0; p < 4; ++p) {
        if (p) __syncthreads();       // first pass covered by main loop's final barrier
        // Y + deg: owning wave (dir, wl==p) writes to its dir-indexed slice
        if (wl == p) {
#pragma unroll
            for (int rt = 0; rt < 2; ++rt)
#pragma unroll
                for (int nt = 0; nt < 4; ++nt)
#pragma unroll
                    for (int r = 0; r < 4; ++r)
                        smf[YB_f + dir * YST + (16 * rt + 4 * lg + r) * 69 + nt * 16 + lm] = acc[rt][nt][r];
            if (lm == 0)
#pragma unroll
                for (int rt = 0; rt < 2; ++rt)
#pragma unroll
                    for (int r = 0; r < 4; ++r)
                        smf[DG_f + dir * 32 + 16 * rt + 4 * lg + r] = dacc[rt][r];
        }
        // W stage: each half stages its own dir's W (coalesced float4)
        {
            const float* Wp = (q ? W_out : W_in) + p * Dsz * Dsz;
            const int r = t2 >> 2, cq = t2 & 3;
#pragma unroll
            for (int k = 0; k < 4; ++k)
                *(float4*)&smf[WB_f + q * WST + r * 68 + 16 * cq + 4 * k] =
                    *(const float4*)&Wp[r * Dsz + 16 * cq + 4 * k];
        }
        {
            const float* wgp = (q ? wg_out : wg_in) + p * Dsz;
            const float* bpS = (q ? b_out  : b_in)  + p * Dsz;
            if (t2 < 64)        smf[WG_f + q * 64 + t2]      = wgp[t2];
            else if (t2 < 128)  smf[BB_f + q * 64 + t2 - 64] = bpS[t2 - 64];
        }
        const float bg_ = (q ? bg_out : bg_in)[p];
        __syncthreads();

        float dg[4], gate[4], tq[4][2];
#pragma unroll
        for (int r = 0; r < 4; ++r) {
            dg[r]   = smf[DG_f + q * 32 + 4 * er + r];
            gate[r] = dg[r] * bg_;
            tq[r][0] = dg[r] * smf[BB_f + q * 64 + 2 * ec];
            tq[r][1] = dg[r] * smf[BB_f + q * 64 + 2 * ec + 1];
        }
#pragma unroll 4
        for (int e = 0; e < 64; ++e) {
            const float wgv = smf[WG_f + q * 64 + e];
            const float2 wv = *(const float2*)&smf[WB_f + q * WST + e * 68 + 2 * ec];
#pragma unroll
            for (int r = 0; r < 4; ++r) {
                const float yv = smf[YB_f + q * YST + (4 * er + r) * 69 + e];
                gate[r]  += yv * wgv;
                tq[r][0] += yv * wv.x;
                tq[r][1] += yv * wv.y;
            }
        }
#pragma unroll
        for (int r = 0; r < 4; ++r) {
            const float sg = 1.f / (1.f + expf(-gate[r]));
            fin2[r][0] += tq[r][0] * sg;
            fin2[r][1] += tq[r][1] * sg;
        }
    }

    // ---- combine halves (q=1 -> LDS -> q=0 adds) and write out
    __syncthreads();
    if (q == 1) {
#pragma unroll
        for (int r = 0; r < 4; ++r) {
            smf[FXB + t2 * 9 + 2 * r]     = fin2[r][0];
            smf[FXB + t2 * 9 + 2 * r + 1] = fin2[r][1];
        }
    }
    __syncthreads();
    if (q == 0) {
        const float inv = 1.f / (3.f * nw[b]);
#pragma unroll
        for (int r = 0; r < 4; ++r) {
            const int row = i0 + 4 * er + r;
            const float2 xr = *(const float2*)&Xb[(size_t)row * Dsz + 2 * ec];
            float2 o;
            o.x = (xr.x + fin2[r][0] + smf[FXB + t2 * 9 + 2 * r])     * inv;
            o.y = (xr.y + fin2[r][1] + smf[FXB + t2 * 9 + 2 * r + 1]) * inv;
            *(float2*)(out + ((size_t)b * Ssz + row) * Dsz + 2 * ec) = o;
        }
    }
}

extern "C" void kernel_launch(void* const* d_in, const int* in_sizes, int n_in,
                              void* d_out, int out_size, void* d_ws, size_t ws_size,
                              hipStream_t stream)
{
    const float* X      = (const float*)d_in[0];
    const int*   adj    = (const int*)  d_in[1];
    const float* nw     = (const float*)d_in[2];
    const float* W_in   = (const float*)d_in[3];
    const float* b_in   = (const float*)d_in[4];
    const float* wg_in  = (const float*)d_in[5];
    const float* bg_in  = (const float*)d_in[6];
    const float* W_out  = (const float*)d_in[7];
    const float* b_out  = (const float*)d_in[8];
    const float* wg_out = (const float*)d_in[9];
    const float* bg_out = (const float*)d_in[10];
    float* out = (float*)d_out;

    dim3 grid(Ssz / TI, Bsz);   // (16, 32) = 512 blocks -> 2/CU
    dim3 block(512);
    hipLaunchKernelGGL(rfgcn_mfma, grid, block, 0, stream,
                       X, adj, nw, W_in, b_in, wg_in, bg_in,
                       W_out, b_out, wg_out, bg_out, out);
}